// Round 2
// baseline (373.902 us; speedup 1.0000x reference)
//
#include <hip/hip_runtime.h>
#include <hip/hip_bf16.h>
#include <stdint.h>

// EncoderBlock: x(4,1024,768) -> MHA(12 heads, D=64) -> +res, LN -> FFN(3072,ReLU) -> +res, LN
// Output buffer FP32 (verified via out_npz size ~11.65MB = 3.15M fp32). Inputs fp32.
// Internal compute bf16 MFMA with fp32 accumulation.

typedef __bf16 bf16;
typedef __attribute__((ext_vector_type(4))) __bf16 bf16x4;
typedef __attribute__((ext_vector_type(8))) __bf16 bf16x8;
typedef __attribute__((ext_vector_type(4))) float f32x4;

#define TOK 4096
#define MDIM 768
#define HH 12
#define FFD 3072

static __device__ __forceinline__ void gload_lds16(const bf16* g, bf16* l) {
  __builtin_amdgcn_global_load_lds(
      (const __attribute__((address_space(1))) unsigned int*)g,
      (__attribute__((address_space(3))) unsigned int*)l, 16, 0, 0);
}

static __device__ __forceinline__ f32x4 mfma16(bf16x8 a, bf16x8 b, f32x4 c) {
  return __builtin_amdgcn_mfma_f32_16x16x32_bf16(a, b, c, 0, 0, 0);
}

// ---------------- prep kernels ----------------

__global__ __launch_bounds__(256) void k_cast_x(const float4* __restrict__ x,
                                                bf16x4* __restrict__ xb, int n4) {
  int i = blockIdx.x * 256 + threadIdx.x;
  if (i >= n4) return;
  float4 v = x[i];
  bf16x4 o = {(bf16)v.x, (bf16)v.y, (bf16)v.z, (bf16)v.w};
  xb[i] = o;
}

// Wq/Wk/Wv (H,M,D) f32 -> Wqkv_t (2304 out-ch, 768 in) bf16, row o = s*768 + h*64 + d
__global__ __launch_bounds__(256) void k_build_wqkv(const float* __restrict__ Wq,
                                                    const float* __restrict__ Wk,
                                                    const float* __restrict__ Wv,
                                                    bf16* __restrict__ dst) {
  int mt = blockIdx.x, h = blockIdx.y, s = blockIdx.z;
  const float* src = (s == 0 ? Wq : s == 1 ? Wk : Wv) + (size_t)h * 768 * 64;
  __shared__ bf16 t[64][65];
  int tid = threadIdx.x;
#pragma unroll
  for (int rep = 0; rep < 16; rep++) {
    int lin = rep * 256 + tid;
    int m = lin >> 6, d = lin & 63;
    t[m][d] = (bf16)src[(size_t)(mt * 64 + m) * 64 + d];
  }
  __syncthreads();
#pragma unroll
  for (int rep = 0; rep < 16; rep++) {
    int lin = rep * 256 + tid;
    int d = lin >> 6, m = lin & 63;
    dst[(size_t)(s * 768 + h * 64 + d) * 768 + mt * 64 + m] = t[m][d];
  }
}

// generic (R,C) f32 -> (C,R) bf16 transpose, 64x64 tiles; grid = (C/64, R/64)
__global__ __launch_bounds__(256) void k_transpose(const float* __restrict__ src,
                                                   bf16* __restrict__ dst, int R, int C) {
  __shared__ bf16 t[64][65];
  int ct = blockIdx.x * 64, rt = blockIdx.y * 64;
  int tid = threadIdx.x;
#pragma unroll
  for (int rep = 0; rep < 16; rep++) {
    int lin = rep * 256 + tid;
    int r = lin >> 6, c = lin & 63;
    t[r][c] = (bf16)src[(size_t)(rt + r) * C + ct + c];
  }
  __syncthreads();
#pragma unroll
  for (int rep = 0; rep < 16; rep++) {
    int lin = rep * 256 + tid;
    int c = lin >> 6, r = lin & 63;
    dst[(size_t)(ct + c) * R + rt + r] = t[r][c];
  }
}

__global__ __launch_bounds__(256) void k_bias_qkv(const float* __restrict__ bq,
                                                  const float* __restrict__ bk,
                                                  const float* __restrict__ bv,
                                                  float* __restrict__ dst) {
  int i = blockIdx.x * 256 + threadIdx.x;
  if (i < 768) dst[i] = bq[i];
  else if (i < 1536) dst[i] = bk[i - 768];
  else if (i < 2304) dst[i] = bv[i - 1536];
}

// ---------------- GEMM (m97 structure: 128x128 tile, BK=64, global_load_lds) ----------------
// A (Mr,K) bf16 row-major; Bt (Nc,K) bf16 row-major (= B transposed).
// EPI 0: scatter to Q/K/V [h][n][k][d] bf16, += bias
// EPI 1: outf fp32 = acc + bias[col] + res[row,col]
// EPI 2: outb bf16 = relu(acc + bias[col])
template <int EPI>
__global__ __launch_bounds__(256) void k_gemm(const bf16* __restrict__ A,
                                              const bf16* __restrict__ Bt,
                                              const float* __restrict__ bias,
                                              const float* __restrict__ res,
                                              float* __restrict__ outf,
                                              bf16* __restrict__ outb,
                                              bf16* __restrict__ q, bf16* __restrict__ kk,
                                              bf16* __restrict__ v,
                                              int Mr, int Nc, int K) {
  __shared__ bf16 As[128 * 64];
  __shared__ bf16 Bs[128 * 64];
  int tid = threadIdx.x, wave = tid >> 6, lane = tid & 63;
  int rb = blockIdx.y * 128, cb = blockIdx.x * 128;
  int wr = (wave >> 1) * 64, wc = (wave & 1) * 64;

  f32x4 acc[4][4];
#pragma unroll
  for (int m = 0; m < 4; m++)
#pragma unroll
    for (int n = 0; n < 4; n++) acc[m][n] = f32x4{0.f, 0.f, 0.f, 0.f};

  for (int k0 = 0; k0 < K; k0 += 64) {
#pragma unroll
    for (int j = 0; j < 4; j++) {
      int row = wave * 32 + j * 8;
      const bf16* ga = A + (size_t)(rb + row + (lane >> 3)) * K + k0 + (lane & 7) * 8;
      gload_lds16(ga, &As[row * 64]);
      const bf16* gb = Bt + (size_t)(cb + row + (lane >> 3)) * K + k0 + (lane & 7) * 8;
      gload_lds16(gb, &Bs[row * 64]);
    }
    __syncthreads();
#pragma unroll
    for (int ks = 0; ks < 2; ks++) {
      bf16x8 af[4], bfr[4];
#pragma unroll
      for (int m = 0; m < 4; m++)
        af[m] = *reinterpret_cast<const bf16x8*>(
            &As[(wr + m * 16 + (lane & 15)) * 64 + ks * 32 + (lane >> 4) * 8]);
#pragma unroll
      for (int n = 0; n < 4; n++)
        bfr[n] = *reinterpret_cast<const bf16x8*>(
            &Bs[(wc + n * 16 + (lane & 15)) * 64 + ks * 32 + (lane >> 4) * 8]);
#pragma unroll
      for (int m = 0; m < 4; m++)
#pragma unroll
        for (int n = 0; n < 4; n++) acc[m][n] = mfma16(af[m], bfr[n], acc[m][n]);
    }
    __syncthreads();
  }

#pragma unroll
  for (int m = 0; m < 4; m++) {
#pragma unroll
    for (int n = 0; n < 4; n++) {
      int col = cb + wc + n * 16 + (lane & 15);
#pragma unroll
      for (int r = 0; r < 4; r++) {
        int row = rb + wr + m * 16 + (lane >> 4) * 4 + r;
        float val = acc[m][n][r];
        if (EPI == 0) {
          val += bias[col];
          int sec = col / 768;
          int cm = col - sec * 768;
          int h = cm >> 6, d = cm & 63;
          bf16* dst = (sec == 0 ? q : sec == 1 ? kk : v);
          dst[(((size_t)(h * 4 + (row >> 10))) * 1024 + (row & 1023)) * 64 + d] = (bf16)val;
        } else if (EPI == 1) {
          outf[(size_t)row * Nc + col] = val + bias[col] + res[(size_t)row * Nc + col];
        } else {
          float t = val + bias[col];
          outb[(size_t)row * Nc + col] = (bf16)fmaxf(t, 0.f);
        }
      }
    }
  }
}

// ---------------- fused flash attention ----------------
// grid (16 qtiles, 4 batch, 12 heads), 256 thr. Q,K,V: [h][n][1024][64] bf16.
// Y out: [n*1024+k][h*64+d] bf16 (= concat heads, feeds out-proj GEMM as A).
__global__ __launch_bounds__(256) void k_attn(const bf16* __restrict__ Q,
                                              const bf16* __restrict__ Kb,
                                              const bf16* __restrict__ Vb,
                                              bf16* __restrict__ Y) {
  __shared__ bf16 Vt[64 * 64];      // V tile transposed [d][j], XOR-swizzled rows
  __shared__ bf16 Pl[4 * 16 * 64];  // per-wave P tiles [qrow][j], XOR-swizzled rows
  int qt = blockIdx.x, nb = blockIdx.y, h = blockIdx.z;
  int tid = threadIdx.x, w = tid >> 6, lane = tid & 63;
  size_t hn = (size_t)(h * 4 + nb) * 1024;

  const bf16* qptr = Q + (hn + qt * 64 + w * 16 + (lane & 15)) * 64 + (lane >> 4) * 8;
  bf16x8 qf0 = *(const bf16x8*)qptr;
  bf16x8 qf1 = *(const bf16x8*)(qptr + 32);

  float mreg[4], lreg[4];
  f32x4 oacc[4];
#pragma unroll
  for (int r = 0; r < 4; r++) { mreg[r] = -1e30f; lreg[r] = 0.f; }
#pragma unroll
  for (int dt = 0; dt < 4; dt++) oacc[dt] = f32x4{0.f, 0.f, 0.f, 0.f};
  char* Pw = (char*)Pl + w * 2048;

  for (int kt = 0; kt < 16; kt++) {
    __syncthreads();  // prev iter's PV reads done; Vt/P free to overwrite
    {                 // stage V tile transposed: wave w covers j in [w*16, w*16+16), all d
      const bf16* vsrc = Vb + (hn + kt * 64 + w * 16) * 64 + lane;  // lane = d
      bf16 vv[16];
#pragma unroll
      for (int jj = 0; jj < 16; jj++) vv[jj] = vsrc[(size_t)jj * 64];
#pragma unroll
      for (int half = 0; half < 2; half++) {
        bf16x8 pk;
#pragma unroll
        for (int e = 0; e < 8; e++) pk[e] = vv[half * 8 + e];
        int byte_ = (lane * 128 + w * 32 + half * 16) ^ ((lane & 7) << 4);
        *(bf16x8*)((char*)Vt + byte_) = pk;
      }
    }
    // S = Q K^T (K frags direct from global; L2-resident)
    f32x4 sa[4];
#pragma unroll
    for (int ct = 0; ct < 4; ct++) {
      sa[ct] = f32x4{0.f, 0.f, 0.f, 0.f};
      const bf16* kp = Kb + (hn + kt * 64 + ct * 16 + (lane & 15)) * 64 + (lane >> 4) * 8;
      bf16x8 kf0 = *(const bf16x8*)kp;
      bf16x8 kf1 = *(const bf16x8*)(kp + 32);
      sa[ct] = mfma16(qf0, kf0, sa[ct]);
      sa[ct] = mfma16(qf1, kf1, sa[ct]);
    }
    // online softmax (wave-parallel, 16-lane row reduce)
#pragma unroll
    for (int r = 0; r < 4; r++) {
      float mx = fmaxf(fmaxf(sa[0][r], sa[1][r]), fmaxf(sa[2][r], sa[3][r])) * 0.125f;
#pragma unroll
      for (int off = 1; off < 16; off <<= 1) mx = fmaxf(mx, __shfl_xor(mx, off, 64));
      float mn = fmaxf(mreg[r], mx);
      float alpha = __expf(mreg[r] - mn);
      mreg[r] = mn;
      float rs = 0.f;
      int prow = (lane >> 4) * 4 + r;
#pragma unroll
      for (int ct = 0; ct < 4; ct++) {
        float p = __expf(sa[ct][r] * 0.125f - mn);
        rs += p;
        int byte_ = (prow * 128 + (ct * 16 + (lane & 15)) * 2) ^ ((prow & 7) << 4);
        *(bf16*)(Pw + byte_) = (bf16)p;
      }
#pragma unroll
      for (int off = 1; off < 16; off <<= 1) rs += __shfl_xor(rs, off, 64);
      lreg[r] = lreg[r] * alpha + rs;
#pragma unroll
      for (int dt = 0; dt < 4; dt++) oacc[dt][r] *= alpha;
    }
    __syncthreads();  // Vt writes (all waves) + P writes visible
    // O += P V
#pragma unroll
    for (int s = 0; s < 2; s++) {
      int prow = lane & 15;
      int pb = (prow * 128 + s * 64 + (lane >> 4) * 16) ^ ((prow & 7) << 4);
      bf16x8 pf = *(const bf16x8*)(Pw + pb);
#pragma unroll
      for (int dt = 0; dt < 4; dt++) {
        int vrow = dt * 16 + (lane & 15);
        int vb_ = (vrow * 128 + s * 64 + (lane >> 4) * 16) ^ ((vrow & 7) << 4);
        bf16x8 vf = *(const bf16x8*)((char*)Vt + vb_);
        oacc[dt] = mfma16(pf, vf, oacc[dt]);
      }
    }
  }
#pragma unroll
  for (int dt = 0; dt < 4; dt++) {
#pragma unroll
    for (int r = 0; r < 4; r++) {
      int row = qt * 64 + w * 16 + (lane >> 4) * 4 + r;
      float val = oacc[dt][r] / lreg[r];
      Y[((size_t)nb * 1024 + row) * 768 + h * 64 + dt * 16 + (lane & 15)] = (bf16)val;
    }
  }
}

// ---------------- LayerNorm (1 wave per row) ----------------
__global__ __launch_bounds__(256) void k_ln(const float* __restrict__ u,
                                            const float* __restrict__ gam,
                                            const float* __restrict__ bet,
                                            float* __restrict__ of, bf16* __restrict__ ob,
                                            int nrows) {
  int row = blockIdx.x * 4 + (threadIdx.x >> 6);
  int lane = threadIdx.x & 63;
  if (row >= nrows) return;
  const float* ur = u + (size_t)row * 768;
  float v[12];
  float s = 0.f;
#pragma unroll
  for (int e = 0; e < 12; e++) { v[e] = ur[e * 64 + lane]; s += v[e]; }
#pragma unroll
  for (int off = 32; off; off >>= 1) s += __shfl_xor(s, off, 64);
  float mean = s * (1.0f / 768.0f);
  float qv = 0.f;
#pragma unroll
  for (int e = 0; e < 12; e++) { float d = v[e] - mean; qv += d * d; }
#pragma unroll
  for (int off = 32; off; off >>= 1) qv += __shfl_xor(qv, off, 64);
  float rstd = rsqrtf(qv * (1.0f / 768.0f) + 1e-10f);
#pragma unroll
  for (int e = 0; e < 12; e++) {
    int c = e * 64 + lane;
    float o = gam[c] * (v[e] - mean) * rstd + bet[c];
    if (of) of[(size_t)row * 768 + c] = o;
    if (ob) ob[(size_t)row * 768 + c] = (bf16)o;
  }
}

// ---------------- launch ----------------
extern "C" void kernel_launch(void* const* d_in, const int* in_sizes, int n_in,
                              void* d_out, int out_size, void* d_ws, size_t ws_size,
                              hipStream_t stream) {
  const float* x   = (const float*)d_in[0];
  const float* Wq  = (const float*)d_in[1];
  const float* bq  = (const float*)d_in[2];
  const float* Wk  = (const float*)d_in[3];
  const float* bk  = (const float*)d_in[4];
  const float* Wv  = (const float*)d_in[5];
  const float* bv  = (const float*)d_in[6];
  const float* Wo  = (const float*)d_in[7];
  const float* bo  = (const float*)d_in[8];
  const float* g1  = (const float*)d_in[9];
  const float* be1 = (const float*)d_in[10];
  const float* g2  = (const float*)d_in[11];
  const float* be2 = (const float*)d_in[12];
  const float* W1  = (const float*)d_in[13];
  const float* bf1 = (const float*)d_in[14];
  const float* W2  = (const float*)d_in[15];
  const float* bf2 = (const float*)d_in[16];
  float* dout = (float*)d_out;  // fp32 output

  char* p = (char*)d_ws;
  auto alloc = [&](size_t bytes) -> char* {
    char* r = p;
    p += (bytes + 255) & ~(size_t)255;
    return r;
  };
  bf16* xb      = (bf16*)alloc((size_t)TOK * MDIM * 2);
  bf16* wqkv_t  = (bf16*)alloc((size_t)2304 * 768 * 2);
  bf16* wo_t    = (bf16*)alloc((size_t)768 * 768 * 2);
  bf16* w1_t    = (bf16*)alloc((size_t)FFD * 768 * 2);
  bf16* w2_t    = (bf16*)alloc((size_t)768 * FFD * 2);
  float* biasq  = (float*)alloc(2304 * 4);
  bf16* qb      = (bf16*)alloc((size_t)HH * TOK * 64 * 2);
  bf16* kb      = (bf16*)alloc((size_t)HH * TOK * 64 * 2);
  bf16* vb      = (bf16*)alloc((size_t)HH * TOK * 64 * 2);
  bf16* yb      = (bf16*)alloc((size_t)TOK * MDIM * 2);
  float* u1     = (float*)alloc((size_t)TOK * MDIM * 4);
  float* o1f    = (float*)alloc((size_t)TOK * MDIM * 4);
  bf16* o1b     = (bf16*)alloc((size_t)TOK * MDIM * 2);
  bf16* ff1     = (bf16*)alloc((size_t)TOK * FFD * 2);
  float* u2     = (float*)alloc((size_t)TOK * MDIM * 4);

  k_cast_x<<<TOK * MDIM / 4 / 256, 256, 0, stream>>>((const float4*)x, (bf16x4*)xb,
                                                     TOK * MDIM / 4);
  k_build_wqkv<<<dim3(12, 12, 3), 256, 0, stream>>>(Wq, Wk, Wv, wqkv_t);
  k_transpose<<<dim3(12, 12), 256, 0, stream>>>(Wo, wo_t, 768, 768);
  k_transpose<<<dim3(48, 12), 256, 0, stream>>>(W1, w1_t, 768, FFD);
  k_transpose<<<dim3(12, 48), 256, 0, stream>>>(W2, w2_t, FFD, 768);
  k_bias_qkv<<<9, 256, 0, stream>>>(bq, bk, bv, biasq);

  k_gemm<0><<<dim3(2304 / 128, TOK / 128), 256, 0, stream>>>(
      xb, wqkv_t, biasq, nullptr, nullptr, nullptr, qb, kb, vb, TOK, 2304, 768);
  k_attn<<<dim3(16, 4, 12), 256, 0, stream>>>(qb, kb, vb, yb);
  k_gemm<1><<<dim3(768 / 128, TOK / 128), 256, 0, stream>>>(
      yb, wo_t, bo, x, u1, nullptr, nullptr, nullptr, nullptr, TOK, 768, 768);
  k_ln<<<TOK / 4, 256, 0, stream>>>(u1, g1, be1, o1f, o1b, TOK);
  k_gemm<2><<<dim3(FFD / 128, TOK / 128), 256, 0, stream>>>(
      o1b, w1_t, bf1, nullptr, nullptr, ff1, nullptr, nullptr, nullptr, TOK, FFD, 768);
  k_gemm<1><<<dim3(768 / 128, TOK / 128), 256, 0, stream>>>(
      ff1, w2_t, bf2, o1f, u2, nullptr, nullptr, nullptr, nullptr, TOK, 768, FFD);
  k_ln<<<TOK / 4, 256, 0, stream>>>(u2, g2, be2, dout, nullptr, TOK);
}